// Round 8
// baseline (153.453 us; speedup 1.0000x reference)
//
#include <hip/hip_runtime.h>

namespace {

constexpr int NV = 512;
constexpr unsigned WMAX = 0xFFFFFFFFu;
typedef unsigned long long ull;
constexpr ull INF64 = ~0ULL;

// Edge total order = reference's stable sort: (f32 weight bits, triu index).
// triu index is order-isomorphic to lex (i,j), i<j, so the canonical key
// (w_bits<<32)|(i<<9)|j induces the identical order (w>=0 -> bits monotone).
// Keys globally unique -> unique MST -> Boruvka (contracted or not) accepts
// exactly Kruskal's edge set; all combining is via min -> deterministic.
__global__ __launch_bounds__(1024) void boruvka_loss(
    const float* __restrict__ d1, const float* __restrict__ d2,
    float* __restrict__ partial)
{
    const int blk = blockIdx.x;
    const float* __restrict__ Dm = blk ? d2 : d1;
    const float* __restrict__ Do = blk ? d1 : d2;
    const int tid = threadIdx.x;
    const int lane = tid & 63;
    const int wid = tid >> 6;

    __shared__ ull R[128 * 128];                  // dense symmetric contracted keys (128 KiB)
    __shared__ __align__(16) unsigned comp[NV];   // vertex -> comp root, then dense id
    __shared__ ull best[NV];                      // vertex rounds: per-comp min key
    __shared__ unsigned parent[NV];               // hook forest / present flags
    __shared__ unsigned dmap[NV];                 // root -> dense id
    __shared__ ull bestK[128];                    // contracted rounds: per-comp min key
    __shared__ unsigned cc[128];                  // dense id -> current root (dense)
    __shared__ unsigned cpar[128];
    __shared__ unsigned waveSum[8];
    __shared__ float red[17];
    __shared__ int accTot, doneFlag;

    if (tid < NV) { comp[tid] = tid; best[tid] = INF64; }
    if (tid == 0) { accTot = 0; doneFlag = 0; }

    const int v  = tid >> 1;               // 2 threads per row
    const int c0 = (tid & 1) << 8;         // column half 0 / 256
    const float4* __restrict__ rowp4 =
        reinterpret_cast<const float4*>(Dm + ((size_t)v << 9) + c0);
    const uint4* comp4 = reinterpret_cast<const uint4*>(&comp[c0]);

    float contrib  = 0.f;                  // vertex rounds (all threads)
    float contrib2 = 0.f;                  // contracted rounds (wave 0)

    __syncthreads();

    // ================= vertex-level rounds 0,1 (R3 structure) =================
    for (int round = 0; round < 2; ++round) {
        // ---- scan: first-wins ascending keeps canonical smallest column
        {
            const unsigned cv = comp[v];
            unsigned wmin = WMAX, umin = 0;
            bool any = false;
#pragma unroll 4
            for (int s = 0; s < 64; ++s) {
                float4 w4 = rowp4[s];
                uint4  q4 = comp4[s];
                unsigned wb;
                wb = __float_as_uint(w4.x);
                if ((q4.x != cv) && (!any || wb < wmin)) { wmin = wb; umin = c0 + s*4 + 0; any = true; }
                wb = __float_as_uint(w4.y);
                if ((q4.y != cv) && (wb < wmin || !any)) { wmin = wb; umin = c0 + s*4 + 1; any = true; }
                wb = __float_as_uint(w4.z);
                if ((q4.z != cv) && (wb < wmin || !any)) { wmin = wb; umin = c0 + s*4 + 2; any = true; }
                wb = __float_as_uint(w4.w);
                if ((q4.w != cv) && (wb < wmin || !any)) { wmin = wb; umin = c0 + s*4 + 3; any = true; }
            }
            if (any) {
                unsigned uv = (unsigned)v;
                unsigned lo = (umin < uv) ? ((umin << 9) | uv) : ((uv << 9) | umin);
                atomicMin(&best[cv], ((ull)wmin << 32) | (ull)lo);
            }
        }
        __syncthreads();

        // ---- hook
        ull he = INF64; unsigned hp = 0, hlo = 0;
        if (tid < NV) {
            unsigned t = (unsigned)tid;
            he = best[t];
            hp = t;
            if (he != INF64) {
                hlo = (unsigned)he & 0x3FFFFu;
                unsigned ci = comp[hlo >> 9], cj = comp[hlo & 511u];
                hp = (ci == t) ? cj : ci;
            }
            parent[t] = hp;
        }
        __syncthreads();

        // ---- break 2-cycles
        if (tid < NV) {
            unsigned t = (unsigned)tid, p = parent[t];
            if (p != t && parent[p] == t && t < p) parent[t] = t;
        }
        __syncthreads();

        // ---- accept (dedup mutual picks by unique key)
        if (tid < NV && he != INF64) {
            bool dup = (best[hp] == he) && (hp < (unsigned)tid);
            if (!dup) {
                float a = __uint_as_float((unsigned)(he >> 32));
                float b = Do[hlo];                 // (i<<9)|j == i*512+j
                float d = a - b;
                contrib += d * d;
                atomicAdd(&accTot, 1);
            }
        }

        // ---- pointer jumping (9 doublings)
        for (int jt = 0; jt < 9; ++jt) {
            __syncthreads();
            if (tid < NV) parent[tid] = parent[parent[tid]];
        }
        __syncthreads();
        if (tid < NV) {
            comp[tid] = parent[comp[tid]];
            best[tid] = INF64;
        }
        __syncthreads();
        if (accTot == NV - 1) break;               // uniform post-barrier
    }

    if (accTot < NV - 1) {
        // ============ renumber comp roots to dense ids [0,C), C<=128 ============
        if (tid < NV) parent[tid] = 0;
        __syncthreads();
        if (tid < NV) parent[comp[tid]] = 1;       // benign write races
        __syncthreads();
        unsigned bit = 0, rank = 0;
        if (tid < NV) {
            bit = parent[tid];
            ull m = __ballot(bit != 0);
            rank = (unsigned)__popcll(m & ((1ull << lane) - 1ull));
            if (lane == 0) waveSum[wid] = (unsigned)__popcll(m);
        }
        __syncthreads();
        if (tid == 0) {
            unsigned run = 0;
#pragma unroll
            for (int w = 0; w < 8; ++w) { unsigned t = waveSum[w]; waveSum[w] = run; run += t; }
        }
        __syncthreads();
        if (tid < NV && bit) dmap[tid] = waveSum[wid] + rank;
        __syncthreads();
        if (tid < NV) comp[tid] = dmap[comp[tid]];
        __syncthreads();

        // ============ contraction: dense symmetric R (prune-read + atomicMin) ===
        for (int s = tid; s < 128 * 128; s += 1024) R[s] = INF64;
        if (tid < 128) { cc[tid] = tid; bestK[tid] = INF64; }
        __syncthreads();
        {
            const unsigned cvd = comp[v];
            const int d = v - c0;
            if (d < 256) {
                const int sLo = (d < 0) ? 0 : (d >> 2);
                const volatile unsigned* Rh = reinterpret_cast<const volatile unsigned*>(R);
                for (int s = sLo; s < 64; ++s) {
                    float4 w4 = rowp4[s];
                    uint4  q4 = comp4[s];
                    const int u0 = c0 + s * 4;
                    unsigned wb[4] = {__float_as_uint(w4.x), __float_as_uint(w4.y),
                                      __float_as_uint(w4.z), __float_as_uint(w4.w)};
                    unsigned dq[4] = {q4.x, q4.y, q4.z, q4.w};
#pragma unroll
                    for (int k = 0; k < 4; ++k) {
                        int u = u0 + k;
                        if (u > v && dq[k] != cvd) {
                            ull key = ((ull)wb[k] << 32) | (ull)(((unsigned)v << 9) | (unsigned)u);
                            int idx = (int)cvd * 128 + (int)dq[k];
                            // prune on the weight word (<= keeps equal-weight lo ties correct)
                            if (wb[k] <= Rh[2 * idx + 1]) {
                                atomicMin(&R[idx], key);
                                atomicMin(&R[(int)dq[k] * 128 + (int)cvd], key);
                            }
                        }
                    }
                }
            }
        }
        __syncthreads();

        // ============ contracted rounds: atomic-free row reduce ============
        for (int rep = 0; rep < 8 && accTot < NV - 1; ++rep) {
            // ---- scan: 8 threads per row; shuffle-reduce; <=128 pruned atomics
            {
                const int a = tid >> 3, sub = tid & 7;
                const unsigned ca = cc[a];
                const ull* __restrict__ rowR = &R[a * 128 + sub * 16];
                const unsigned* __restrict__ ccb = &cc[sub * 16];
                ull m = INF64;
#pragma unroll
                for (int k = 0; k < 16; ++k) {
                    ull e = rowR[k];
                    if (ccb[k] != ca && e < m) m = e;
                }
#pragma unroll
                for (int off = 1; off < 8; off <<= 1) {
                    ull o = __shfl_xor(m, off);
                    if (o < m) m = o;
                }
                if (sub == 0 && m != INF64 && bestK[ca] > m) atomicMin(&bestK[ca], m);
            }
            __syncthreads();

            // ---- merge: wave 0, 2 comps/lane, fence-separated
            if (tid < 64) {
                const unsigned t0 = (unsigned)lane, t1 = (unsigned)lane + 64u;
                ull e0 = bestK[t0], e1 = bestK[t1];
                unsigned p0 = t0, p1 = t1;
                if (e0 != INF64) {
                    unsigned lo = (unsigned)e0 & 0x3FFFFu;
                    unsigned ci = cc[comp[lo >> 9]], cj = cc[comp[lo & 511u]];
                    p0 = (ci == t0) ? cj : ci;
                }
                if (e1 != INF64) {
                    unsigned lo = (unsigned)e1 & 0x3FFFFu;
                    unsigned ci = cc[comp[lo >> 9]], cj = cc[comp[lo & 511u]];
                    p1 = (ci == t1) ? cj : ci;
                }
                cpar[t0] = p0; cpar[t1] = p1;
                __threadfence_block();
                {
                    unsigned p = cpar[t0];
                    if (p != t0 && cpar[p] == t0 && t0 < p) cpar[t0] = t0;
                    p = cpar[t1];
                    if (p != t1 && cpar[p] == t1 && t1 < p) cpar[t1] = t1;
                }
                __threadfence_block();
                bool take0 = (e0 != INF64) && !((bestK[p0] == e0) && (p0 < t0));
                bool take1 = (e1 != INF64) && !((bestK[p1] == e1) && (p1 < t1));
                if (take0) {
                    unsigned lo = (unsigned)e0 & 0x3FFFFu;
                    float a = __uint_as_float((unsigned)(e0 >> 32));
                    float dd = a - Do[lo];
                    contrib2 += dd * dd;
                }
                if (take1) {
                    unsigned lo = (unsigned)e1 & 0x3FFFFu;
                    float a = __uint_as_float((unsigned)(e1 >> 32));
                    float dd = a - Do[lo];
                    contrib2 += dd * dd;
                }
                int cnt = __popcll(__ballot(take0)) + __popcll(__ballot(take1));
                {
                    unsigned r = cc[t0];
                    while (cpar[r] != r) r = cpar[r];
                    cc[t0] = r;
                    r = cc[t1];
                    while (cpar[r] != r) r = cpar[r];
                    cc[t1] = r;
                }
                __threadfence_block();
                bestK[t0] = INF64; bestK[t1] = INF64;
                if (lane == 0) accTot += cnt;
            }
            __syncthreads();
        }
    }

    // ================= deterministic reduction =================
#pragma unroll
    for (int off = 32; off >= 1; off >>= 1) contrib += __shfl_xor(contrib, off);
    if (lane == 0) red[wid] = contrib;          // 16 wave slots
    if (tid < 64) {
#pragma unroll
        for (int off = 32; off >= 1; off >>= 1) contrib2 += __shfl_xor(contrib2, off);
        if (lane == 0) red[16] = contrib2;
    }
    __syncthreads();
    if (tid == 0) {
        float s = 0.f;
#pragma unroll
        for (int w = 0; w < 17; ++w) s += red[w];
        partial[blk] = s;
    }
}

__global__ void final_add(const float* __restrict__ partial, float* __restrict__ out) {
    out[0] = partial[0] + partial[1];
}

} // namespace

extern "C" void kernel_launch(void* const* d_in, const int* in_sizes, int n_in,
                              void* d_out, int out_size, void* d_ws, size_t ws_size,
                              hipStream_t stream) {
    const float* d1 = (const float*)d_in[0];
    const float* d2 = (const float*)d_in[1];
    float* out = (float*)d_out;
    float* ws = (float*)d_ws;

    boruvka_loss<<<2, 1024, 0, stream>>>(d1, d2, ws); // writes ws[0], ws[1]
    final_add<<<1, 1, 0, stream>>>(ws, out);
}